// Round 23
// baseline (423.897 us; speedup 1.0000x reference)
//
#include <hip/hip_runtime.h>
#include <hip/hip_bf16.h>

#define HD 128
#define NT 6

typedef unsigned short u16;
typedef unsigned int u32;
typedef __attribute__((ext_vector_type(8))) short bf16x8;
typedef __attribute__((ext_vector_type(4))) float f32x4;

__device__ __forceinline__ float sigmoidf_(float x) {
  return 1.0f / (1.0f + __expf(-x));
}

// f32 -> bf16 (RNE)
__device__ __forceinline__ u16 f2bf(float x) {
  u32 u = __float_as_uint(x);
  return (u16)((u + 0x7FFFu + ((u >> 16) & 1u)) >> 16);
}
__device__ __forceinline__ float bflo(u32 v) { return __uint_as_float(v << 16); }
__device__ __forceinline__ float bfhi(u32 v) { return __uint_as_float(v & 0xffff0000u); }
__device__ __forceinline__ float bfs(u16 v) { return __uint_as_float((u32)v << 16); }

// XOR swizzle for 256B-row bf16 LDS tiles (involution, both sides).
__device__ __forceinline__ int swz(int p) { return p ^ (((p >> 8) & 7) << 4); }

// ============ weight convert+transpose: W^T bf16 ============
// WeT: [6][128 cols][128 k]; WgT: [6][128][128] (ir,iz,in,hr,hz,hn)
__global__ void k_cvt_w(const float* __restrict__ We,
                        const float* __restrict__ Wir, const float* __restrict__ Wiz,
                        const float* __restrict__ Win, const float* __restrict__ Whr,
                        const float* __restrict__ Whz, const float* __restrict__ Whn,
                        u16* __restrict__ WeT, u16* __restrict__ WgT) {
  int i = blockIdx.x * blockDim.x + threadIdx.x;
  if (i < NT * HD * HD) {
    int c = i >> 7, k = i & 127;                 // WeT[c][k] = We[k][c]
    WeT[i] = f2bf(We[(size_t)k * (NT * HD) + c]);
  } else {
    int j = i - NT * HD * HD;
    if (j < 6 * HD * HD) {
      int m = j >> 14, jj = j & 16383;
      int c = jj >> 7, k = jj & 127;
      const float* W = (m == 0) ? Wir : (m == 1) ? Wiz : (m == 2) ? Win
                     : (m == 3) ? Whr : (m == 4) ? Whz : Whn;
      WgT[j] = f2bf(W[(size_t)k * HD + c]);
    }
  }
}

// ============ Edge projection GEMM, all 6 types per block (proven form) ============
__global__ __launch_bounds__(256) void k_gemm_edge6(
    const float* __restrict__ X, const u16* __restrict__ WeT,
    const float* __restrict__ Be, u16* __restrict__ P, int N)
{
  __shared__ char As[32768];   // 128 rows x 128 k bf16 (swizzled)
  __shared__ char Bs[32768];
  const int tid = threadIdx.x;
  const int row0 = blockIdx.x * 128;

  #pragma unroll
  for (int i = 0; i < 8; ++i) {
    int p = i * 4096 + tid * 16;
    int row = row0 + (p >> 8);
    union { u16 u[8]; bf16x8 v; } ra;
    if (row < N) {
      const float4* s = (const float4*)(X + (size_t)row0 * HD + (p >> 1));
      float4 f0 = s[0], f1 = s[1];
      ra.u[0] = f2bf(f0.x); ra.u[1] = f2bf(f0.y); ra.u[2] = f2bf(f0.z); ra.u[3] = f2bf(f0.w);
      ra.u[4] = f2bf(f1.x); ra.u[5] = f2bf(f1.y); ra.u[6] = f2bf(f1.z); ra.u[7] = f2bf(f1.w);
    } else {
      #pragma unroll
      for (int j = 0; j < 8; ++j) ra.u[j] = 0;
    }
    *(bf16x8*)(As + swz(p)) = ra.v;
  }

  const int l = tid & 63, w = tid >> 6;
  const int m0 = (w >> 1) * 64, n0 = (w & 1) * 64;
  const int lr = l & 15, lg = l >> 4;
  f32x4 zero = {0.f, 0.f, 0.f, 0.f};

  for (int t = 0; t < NT; ++t) {     // compile-time constant -> unrolled
    __syncthreads();
    const char* gB = (const char*)(WeT + (size_t)t * HD * HD);
    #pragma unroll
    for (int i = 0; i < 8; ++i) {
      int p = i * 4096 + tid * 16;
      *(bf16x8*)(Bs + swz(p)) = *(const bf16x8*)(gB + p);
    }
    __syncthreads();

    f32x4 acc[4][4];
    #pragma unroll
    for (int m = 0; m < 4; ++m)
      #pragma unroll
      for (int n = 0; n < 4; ++n) acc[m][n] = zero;

    #pragma unroll
    for (int k = 0; k < 4; ++k) {
      bf16x8 a[4], b[4];
      #pragma unroll
      for (int m = 0; m < 4; ++m)
        a[m] = *(const bf16x8*)(As + swz((m0 + m * 16 + lr) * 256 + k * 64 + lg * 16));
      #pragma unroll
      for (int n = 0; n < 4; ++n)
        b[n] = *(const bf16x8*)(Bs + swz((n0 + n * 16 + lr) * 256 + k * 64 + lg * 16));
      #pragma unroll
      for (int m = 0; m < 4; ++m)
        #pragma unroll
        for (int n = 0; n < 4; ++n)
          acc[m][n] = __builtin_amdgcn_mfma_f32_16x16x32_bf16(a[m], b[n], acc[m][n], 0, 0, 0);
    }

    float bias[4];
    #pragma unroll
    for (int n = 0; n < 4; ++n) bias[n] = Be[t * HD + n0 + n * 16 + lr];
    #pragma unroll
    for (int m = 0; m < 4; ++m) {
      int rbase = row0 + m0 + m * 16 + lg * 4;
      #pragma unroll
      for (int j = 0; j < 4; ++j) {
        int row = rbase + j;
        if (row < N) {
          #pragma unroll
          for (int n = 0; n < 4; ++n)
            P[(size_t)row * (NT * HD) + t * HD + n0 + n * 16 + lr] =
                f2bf(acc[m][n][j] + bias[n]);
        }
      }
    }
  }
}

// ============ CSR build ============
__global__ __launch_bounds__(256) void k_count(const int* __restrict__ dst,
                                               const int* __restrict__ nePtr,
                                               int* __restrict__ deg) {
  const int ne = nePtr[0];
  for (int e = blockIdx.x * blockDim.x + threadIdx.x; e < ne;
       e += gridDim.x * blockDim.x)
    atomicAdd(&deg[dst[e]], 1);
}

__global__ __launch_bounds__(256) void k_scan_a(const int* __restrict__ deg,
                                                int* __restrict__ off,
                                                int* __restrict__ bsum, int N) {
  __shared__ int s[256];
  const int b = blockIdx.x, tid = threadIdx.x;
  const int base = b * 1024 + tid * 4;
  int v0 = 0, v1 = 0, v2 = 0, v3 = 0;
  if (base < N) v0 = deg[base];
  if (base + 1 < N) v1 = deg[base + 1];
  if (base + 2 < N) v2 = deg[base + 2];
  if (base + 3 < N) v3 = deg[base + 3];
  const int sum = v0 + v1 + v2 + v3;
  s[tid] = sum;
  __syncthreads();
  for (int d = 1; d < 256; d <<= 1) {
    int t = (tid >= d) ? s[tid - d] : 0;
    __syncthreads();
    s[tid] += t;
    __syncthreads();
  }
  const int excl = s[tid] - sum;
  if (base < N) off[base] = excl;
  if (base + 1 < N) off[base + 1] = excl + v0;
  if (base + 2 < N) off[base + 2] = excl + v0 + v1;
  if (base + 3 < N) off[base + 3] = excl + v0 + v1 + v2;
  if (tid == 255) bsum[b] = s[255];
}

__global__ void k_scan_b(int* __restrict__ bsum, int nb) {
  __shared__ int s[1024];
  const int tid = threadIdx.x;
  const int v = (tid < nb) ? bsum[tid] : 0;
  s[tid] = v;
  __syncthreads();
  for (int d = 1; d < 1024; d <<= 1) {
    int t = (tid >= d) ? s[tid - d] : 0;
    __syncthreads();
    s[tid] += t;
    __syncthreads();
  }
  if (tid < nb) bsum[tid] = s[tid] - v;   // exclusive
}

__global__ __launch_bounds__(256) void k_scan_c(int* __restrict__ off,
                                                const int* __restrict__ bsum, int N) {
  const int b = blockIdx.x, tid = threadIdx.x;
  const int add = bsum[b];
  const int base = b * 1024 + tid * 4;
  #pragma unroll
  for (int i = 0; i < 4; ++i)
    if (base + i < N) off[base + i] += add;
}

__global__ __launch_bounds__(256) void k_fill(const int* __restrict__ src,
                                              const int* __restrict__ dst,
                                              const int* __restrict__ typ,
                                              const int* __restrict__ nePtr,
                                              int* __restrict__ off,
                                              u32* __restrict__ elist) {
  const int ne = nePtr[0];
  for (int e = blockIdx.x * blockDim.x + threadIdx.x; e < ne;
       e += gridDim.x * blockDim.x) {
    int pos = atomicAdd(&off[dst[e]], 1);
    elist[pos] = (u32)(src[e] * NT + typ[e]);   // P-row index
  }
}

// ============ Standalone gather: one wave per node, masked 4-deep MLP ============
__global__ __launch_bounds__(256) void k_gather(
    const u16* __restrict__ P, const int* __restrict__ deg,
    const int* __restrict__ off, const u32* __restrict__ elist,
    u16* __restrict__ Hb, int N)
{
  const int l = threadIdx.x & 63;
  int wid = (int)((blockIdx.x * blockDim.x + threadIdx.x) >> 6);
  int nw = (int)((gridDim.x * blockDim.x) >> 6);
  for (int n = wid; n < N; n += nw) {
    const int e1 = off[n];
    const int e0 = e1 - deg[n];
    float a0 = 0.f, a1 = 0.f, b0 = 0.f, b1 = 0.f;
    for (int e = e0; e < e1; e += 4) {
      u32 p0 = elist[e];
      u32 p1 = (e + 1 < e1) ? elist[e + 1] : p0;
      u32 p2 = (e + 2 < e1) ? elist[e + 2] : p0;
      u32 p3 = (e + 3 < e1) ? elist[e + 3] : p0;
      u32 v0 = *((const u32*)(P + (size_t)p0 * HD) + l);
      u32 v1 = *((const u32*)(P + (size_t)p1 * HD) + l);
      u32 v2 = *((const u32*)(P + (size_t)p2 * HD) + l);
      u32 v3 = *((const u32*)(P + (size_t)p3 * HD) + l);
      if (e + 1 >= e1) v1 = 0;
      if (e + 2 >= e1) v2 = 0;
      if (e + 3 >= e1) v3 = 0;
      a0 += bflo(v0); a1 += bfhi(v0);
      b0 += bflo(v1); b1 += bfhi(v1);
      a0 += bflo(v2); a1 += bfhi(v2);
      b0 += bflo(v3); b1 += bfhi(v3);
    }
    a0 += b0; a1 += b1;
    u32 hp = ((u32)f2bf(a1) << 16) | (u32)f2bf(a0);
    *((u32*)(Hb + (size_t)n * HD) + l) = hp;
  }
}

// ============ GRU v19: B in REGISTERS, barrier-free gate loop ============
// 512 thr / 8 waves / 128-row tile. Wave w owns cols [w*16, w*16+16).
// Per gate: 4x16B B-frag loads from WgT (L2-hot), then 32 MFMA over LDS A.
// Only ONE __syncthreads (after X/H staging). Waves free-run.
__global__ __launch_bounds__(512) void k_gru19(
    const float* __restrict__ X, const u16* __restrict__ Hb,
    const u16* __restrict__ WgT,   // [6][128 cols][128 k]: ir,iz,in,hr,hz,hn
    const float* __restrict__ bir, const float* __restrict__ biz,
    const float* __restrict__ bin_, const float* __restrict__ bhn,
    float* __restrict__ out, int N)
{
  __shared__ char Xs[32768];   // 128 rows x 128 k bf16 (swizzled)
  __shared__ char Hs[32768];
  const int tid = threadIdx.x;
  const int row0 = blockIdx.x * 128;

  // ---- stage X (f32->bf16) and H (bf16 copy) tiles, once ----
  #pragma unroll
  for (int i = 0; i < 4; ++i) {
    int p = i * 8192 + tid * 16;
    int row = row0 + (p >> 8);
    union { u16 u[8]; bf16x8 v; } rx, rh;
    if (row < N) {
      const float4* sx = (const float4*)(X + (size_t)row0 * HD + (p >> 1));
      float4 x0 = sx[0], x1 = sx[1];
      rx.u[0] = f2bf(x0.x); rx.u[1] = f2bf(x0.y); rx.u[2] = f2bf(x0.z); rx.u[3] = f2bf(x0.w);
      rx.u[4] = f2bf(x1.x); rx.u[5] = f2bf(x1.y); rx.u[6] = f2bf(x1.z); rx.u[7] = f2bf(x1.w);
      rh.v = *(const bf16x8*)((const char*)Hb + (size_t)row0 * 256 + p);
    } else {
      #pragma unroll
      for (int j = 0; j < 8; ++j) { rx.u[j] = 0; rh.u[j] = 0; }
    }
    *(bf16x8*)(Xs + swz(p)) = rx.v;
    *(bf16x8*)(Hs + swz(p)) = rh.v;
  }
  __syncthreads();          // the only block-wide barrier

  const int l = tid & 63, w = tid >> 6;
  const int lr = l & 15, lg = l >> 4;
  const int cw = w * 16;                 // wave's 16-col strip
  f32x4 zero = {0.f, 0.f, 0.f, 0.f};

  // load this wave's B-slice for gate g: 4 x bf16x8 (cols cw+lr, k-chunks)
  bf16x8 Bf[4];
  auto loadB = [&](int g) {
    const u16* WT = WgT + (size_t)g * HD * HD;
    #pragma unroll
    for (int kc = 0; kc < 4; ++kc)
      Bf[kc] = *(const bf16x8*)(WT + (size_t)(cw + lr) * HD + kc * 32 + lg * 8);
  };

  // sweep: acc[m] (+)= A-tile @ Bf   (8 m-frags x 4 k-chunks = 32 MFMA)
  auto sweep = [&](const char* Ab, f32x4* acc) {
    #pragma unroll
    for (int m = 0; m < 8; ++m) acc[m] = zero;
    #pragma unroll
    for (int kc = 0; kc < 4; ++kc) {
      #pragma unroll
      for (int m = 0; m < 8; ++m) {
        bf16x8 a = *(const bf16x8*)(Ab + swz((m * 16 + lr) * 256 + kc * 64 + lg * 16));
        acc[m] = __builtin_amdgcn_mfma_f32_16x16x32_bf16(a, Bf[kc], acc[m], 0, 0, 0);
      }
    }
  };

  f32x4 t1[8], t2[8], rg[8], nn[8];
  float bv;

  // gate order: ir(0), hr(3), hn(5), in(2), iz(1), hz(4) — no barriers.
  loadB(0); sweep(Xs, t1);               // X@Wir
  loadB(3); sweep(Hs, t2);               // H@Whr
  bv = bir[cw + lr];
  #pragma unroll
  for (int m = 0; m < 8; ++m)
    #pragma unroll
    for (int j = 0; j < 4; ++j) rg[m][j] = sigmoidf_(t1[m][j] + bv + t2[m][j]);

  loadB(5); sweep(Hs, t2);               // H@Whn
  bv = bhn[cw + lr];
  #pragma unroll
  for (int m = 0; m < 8; ++m)
    #pragma unroll
    for (int j = 0; j < 4; ++j) rg[m][j] *= (t2[m][j] + bv);

  loadB(2); sweep(Xs, t1);               // X@Win
  bv = bin_[cw + lr];
  #pragma unroll
  for (int m = 0; m < 8; ++m)
    #pragma unroll
    for (int j = 0; j < 4; ++j) nn[m][j] = tanhf(t1[m][j] + bv + rg[m][j]);

  loadB(1); sweep(Xs, t1);               // X@Wiz
  loadB(4); sweep(Hs, t2);               // H@Whz
  bv = biz[cw + lr];
  #pragma unroll
  for (int m = 0; m < 8; ++m) {
    #pragma unroll
    for (int j = 0; j < 4; ++j) {
      int row = row0 + m * 16 + lg * 4 + j;
      if (row < N) {
        int col = cw + lr;
        float z = sigmoidf_(t1[m][j] + bv + t2[m][j]);
        float h = bfs(Hb[(size_t)row * HD + col]);   // L3-hot, coalesced
        out[(size_t)row * HD + col] = (1.0f - z) * nn[m][j] + z * h;
      }
    }
  }
}

// ============ Fused gather+GRU (mid-tier fallback) ============
__global__ __launch_bounds__(256) void k_gather_gru(
    const float* __restrict__ X, const u16* __restrict__ P,
    const int* __restrict__ deg, const int* __restrict__ off,
    const u32* __restrict__ elist, const u16* __restrict__ WgT,
    const float* __restrict__ bir, const float* __restrict__ biz,
    const float* __restrict__ bin_, const float* __restrict__ bhn,
    float* __restrict__ out, int N)
{
  __shared__ char Xs[16384];
  __shared__ char Hs[16384];
  const int tid = threadIdx.x;
  const int l = tid & 63, w = tid >> 6;
  const int row0 = blockIdx.x * 64;
  const int wr0 = w * 16;

  #pragma unroll
  for (int it = 0; it < 4; ++it) {
    int chunk = it * 64 + l;
    int r = chunk >> 4, seg = chunk & 15;
    int grow = row0 + wr0 + r;
    union { u16 u[8]; bf16x8 v; } rx;
    if (grow < N) {
      const float4* sx = (const float4*)(X + (size_t)grow * HD + seg * 8);
      float4 x0 = sx[0], x1 = sx[1];
      rx.u[0] = f2bf(x0.x); rx.u[1] = f2bf(x0.y); rx.u[2] = f2bf(x0.z); rx.u[3] = f2bf(x0.w);
      rx.u[4] = f2bf(x1.x); rx.u[5] = f2bf(x1.y); rx.u[6] = f2bf(x1.z); rx.u[7] = f2bf(x1.w);
    } else {
      #pragma unroll
      for (int j = 0; j < 8; ++j) rx.u[j] = 0;
    }
    *(bf16x8*)(Xs + swz((wr0 + r) * 256 + seg * 16)) = rx.v;
  }

  for (int i = 0; i < 16; ++i) {
    int n = row0 + wr0 + i;
    float a0 = 0.f, a1 = 0.f;
    if (n < N) {
      int e1 = off[n];
      for (int e = e1 - deg[n]; e < e1; e += 4) {
        u32 p0 = elist[e];
        u32 p1 = (e + 1 < e1) ? elist[e + 1] : p0;
        u32 p2 = (e + 2 < e1) ? elist[e + 2] : p0;
        u32 p3 = (e + 3 < e1) ? elist[e + 3] : p0;
        u32 v0 = *((const u32*)(P + (size_t)p0 * HD) + l);
        u32 v1 = *((const u32*)(P + (size_t)p1 * HD) + l);
        u32 v2 = *((const u32*)(P + (size_t)p2 * HD) + l);
        u32 v3 = *((const u32*)(P + (size_t)p3 * HD) + l);
        if (e + 1 >= e1) v1 = 0;
        if (e + 2 >= e1) v2 = 0;
        if (e + 3 >= e1) v3 = 0;
        a0 += bflo(v0) + bflo(v1) + bflo(v2) + bflo(v3);
        a1 += bfhi(v0) + bfhi(v1) + bfhi(v2) + bfhi(v3);
      }
    }
    u32 hp = ((u32)f2bf(a1) << 16) | (u32)f2bf(a0);
    *(u32*)(Hs + swz((wr0 + i) * 256 + l * 4)) = hp;
  }

  const int lr = l & 15, lg = l >> 4;
  const int rloc = wr0;

  f32x4 zero = {0.f, 0.f, 0.f, 0.f};
  auto sweep = [&](const char* Ab, const u16* WT, f32x4* acc) {
    #pragma unroll
    for (int n = 0; n < 8; ++n) acc[n] = zero;
    #pragma unroll
    for (int k = 0; k < 4; ++k) {
      bf16x8 a = *(const bf16x8*)(Ab + swz((rloc + lr) * 256 + k * 64 + lg * 16));
      #pragma unroll
      for (int n = 0; n < 8; ++n) {
        bf16x8 b = *(const bf16x8*)(WT + (size_t)(n * 16 + lr) * HD + k * 32 + lg * 8);
        acc[n] = __builtin_amdgcn_mfma_f32_16x16x32_bf16(a, b, acc[n], 0, 0, 0);
      }
    }
  };

  f32x4 t1[8], t2[8], rg[8], nn[8];
  float bv[8];

  sweep(Xs, WgT + 0 * HD * HD, t1);
  sweep(Hs, WgT + 3 * HD * HD, t2);
  #pragma unroll
  for (int n = 0; n < 8; ++n) bv[n] = bir[n * 16 + lr];
  #pragma unroll
  for (int n = 0; n < 8; ++n)
    #pragma unroll
    for (int j = 0; j < 4; ++j) rg[n][j] = sigmoidf_(t1[n][j] + bv[n] + t2[n][j]);

  sweep(Hs, WgT + 5 * HD * HD, t2);
  #pragma unroll
  for (int n = 0; n < 8; ++n) bv[n] = bhn[n * 16 + lr];
  #pragma unroll
  for (int n = 0; n < 8; ++n)
    #pragma unroll
    for (int j = 0; j < 4; ++j) rg[n][j] *= (t2[n][j] + bv[n]);

  sweep(Xs, WgT + 2 * HD * HD, t1);
  #pragma unroll
  for (int n = 0; n < 8; ++n) bv[n] = bin_[n * 16 + lr];
  #pragma unroll
  for (int n = 0; n < 8; ++n)
    #pragma unroll
    for (int j = 0; j < 4; ++j) nn[n][j] = tanhf(t1[n][j] + bv[n] + rg[n][j]);

  sweep(Xs, WgT + 1 * HD * HD, t1);
  sweep(Hs, WgT + 4 * HD * HD, t2);
  #pragma unroll
  for (int n = 0; n < 8; ++n) bv[n] = biz[n * 16 + lr];
  #pragma unroll
  for (int n = 0; n < 8; ++n) {
    #pragma unroll
    for (int j = 0; j < 4; ++j) {
      int row = row0 + rloc + lg * 4 + j;
      if (row < N) {
        float z = sigmoidf_(t1[n][j] + bv[n] + t2[n][j]);
        u16 hu = *(const u16*)(Hs + swz((rloc + lg * 4 + j) * 256 + (n * 16 + lr) * 2));
        out[(size_t)row * HD + n * 16 + lr] = (1.0f - z) * nn[n][j] + z * bfs(hu);
      }
    }
  }
}

// ============ Lowest-tier fallback: atomic scatter + f32-agg GRU ============
__global__ __launch_bounds__(256) void k_scatter(
    const u16* __restrict__ P, const int* __restrict__ src,
    const int* __restrict__ dst, const int* __restrict__ typ,
    const int* __restrict__ nePtr, float* __restrict__ agg,
    int ldP, int fixedType)
{
  const int ne = nePtr[0];
  const int lane = threadIdx.x & 63;
  const int wid = (int)((blockIdx.x * blockDim.x + threadIdx.x) >> 6);
  const int nw = (int)((gridDim.x * blockDim.x) >> 6);
  for (int e = wid; e < ne; e += nw) {
    const int t = typ[e];
    if (fixedType >= 0 && t != fixedType) continue;
    const size_t po = (ldP == HD) ? (size_t)src[e] * HD
                                  : (size_t)src[e] * (NT * HD) + (size_t)t * HD;
    u32 v = *(const u32*)(P + po + lane * 2);
    float* o = agg + (size_t)dst[e] * HD + lane * 2;
    unsafeAtomicAdd(o, bflo(v));
    unsafeAtomicAdd(o + 1, bfhi(v));
  }
}

__global__ __launch_bounds__(256) void k_gru(
    const float* __restrict__ X, const float* __restrict__ agg,
    const u16* __restrict__ WgT,
    const float* __restrict__ bir, const float* __restrict__ biz,
    const float* __restrict__ bin_, const float* __restrict__ bhn,
    float* __restrict__ out, int N)
{
  __shared__ char Xs[16384];
  __shared__ char Hs[16384];
  const int tid = threadIdx.x;
  const int row0 = blockIdx.x * 64;

  #pragma unroll
  for (int i = 0; i < 4; ++i) {
    int p = i * 4096 + tid * 16;
    int row = row0 + (p >> 8);
    union { u16 u[8]; bf16x8 v; } rx, rh;
    if (row < N) {
      const float4* sx = (const float4*)(X + (size_t)row0 * HD + (p >> 1));
      const float4* sh = (const float4*)(agg + (size_t)row0 * HD + (p >> 1));
      float4 x0 = sx[0], x1 = sx[1], h0 = sh[0], h1 = sh[1];
      rx.u[0] = f2bf(x0.x); rx.u[1] = f2bf(x0.y); rx.u[2] = f2bf(x0.z); rx.u[3] = f2bf(x0.w);
      rx.u[4] = f2bf(x1.x); rx.u[5] = f2bf(x1.y); rx.u[6] = f2bf(x1.z); rx.u[7] = f2bf(x1.w);
      rh.u[0] = f2bf(h0.x); rh.u[1] = f2bf(h0.y); rh.u[2] = f2bf(h0.z); rh.u[3] = f2bf(h0.w);
      rh.u[4] = f2bf(h1.x); rh.u[5] = f2bf(h1.y); rh.u[6] = f2bf(h1.z); rh.u[7] = f2bf(h1.w);
    } else {
      #pragma unroll
      for (int j = 0; j < 8; ++j) { rx.u[j] = 0; rh.u[j] = 0; }
    }
    *(bf16x8*)(Xs + swz(p)) = rx.v;
    *(bf16x8*)(Hs + swz(p)) = rh.v;
  }
  __syncthreads();

  const int l = tid & 63, w = tid >> 6;
  const int lr = l & 15, lg = l >> 4;
  const int rloc = w * 16;

  f32x4 zero = {0.f, 0.f, 0.f, 0.f};
  auto sweep = [&](const char* Ab, const u16* WT, f32x4* acc) {
    #pragma unroll
    for (int n = 0; n < 8; ++n) acc[n] = zero;
    #pragma unroll
    for (int k = 0; k < 4; ++k) {
      bf16x8 a = *(const bf16x8*)(Ab + swz((rloc + lr) * 256 + k * 64 + lg * 16));
      #pragma unroll
      for (int n = 0; n < 8; ++n) {
        bf16x8 b = *(const bf16x8*)(WT + (size_t)(n * 16 + lr) * HD + k * 32 + lg * 8);
        acc[n] = __builtin_amdgcn_mfma_f32_16x16x32_bf16(a, b, acc[n], 0, 0, 0);
      }
    }
  };

  f32x4 t1[8], t2[8], rg[8], nn[8];
  float bv[8];

  sweep(Xs, WgT + 0 * HD * HD, t1);
  sweep(Hs, WgT + 3 * HD * HD, t2);
  #pragma unroll
  for (int n = 0; n < 8; ++n) bv[n] = bir[n * 16 + lr];
  #pragma unroll
  for (int n = 0; n < 8; ++n)
    #pragma unroll
    for (int j = 0; j < 4; ++j) rg[n][j] = sigmoidf_(t1[n][j] + bv[n] + t2[n][j]);

  sweep(Hs, WgT + 5 * HD * HD, t2);
  #pragma unroll
  for (int n = 0; n < 8; ++n) bv[n] = bhn[n * 16 + lr];
  #pragma unroll
  for (int n = 0; n < 8; ++n)
    #pragma unroll
    for (int j = 0; j < 4; ++j) rg[n][j] *= (t2[n][j] + bv[n]);

  sweep(Xs, WgT + 2 * HD * HD, t1);
  #pragma unroll
  for (int n = 0; n < 8; ++n) bv[n] = bin_[n * 16 + lr];
  #pragma unroll
  for (int n = 0; n < 8; ++n)
    #pragma unroll
    for (int j = 0; j < 4; ++j) nn[n][j] = tanhf(t1[n][j] + bv[n] + rg[n][j]);

  sweep(Xs, WgT + 1 * HD * HD, t1);
  sweep(Hs, WgT + 4 * HD * HD, t2);
  #pragma unroll
  for (int n = 0; n < 8; ++n) bv[n] = biz[n * 16 + lr];
  #pragma unroll
  for (int n = 0; n < 8; ++n) {
    #pragma unroll
    for (int j = 0; j < 4; ++j) {
      int row = row0 + rloc + lg * 4 + j;
      if (row < N) {
        float z = sigmoidf_(t1[n][j] + bv[n] + t2[n][j]);
        float h = agg[(size_t)row * HD + n * 16 + lr];
        out[(size_t)row * HD + n * 16 + lr] = (1.0f - z) * nn[n][j] + z * h;
      }
    }
  }
}

extern "C" void kernel_launch(void* const* d_in, const int* in_sizes, int n_in,
                              void* d_out, int out_size, void* d_ws, size_t ws_size,
                              hipStream_t stream) {
  const float* X      = (const float*)d_in[0];
  const float* W_edge = (const float*)d_in[1];
  const float* b_edge = (const float*)d_in[2];
  const float* b_ir   = (const float*)d_in[4];
  const float* b_iz   = (const float*)d_in[6];
  const float* b_in   = (const float*)d_in[8];
  const float* b_hn   = (const float*)d_in[12];
  const int* src      = (const int*)d_in[13];
  const int* dst      = (const int*)d_in[14];
  const int* typ      = (const int*)d_in[15];
  const int* nePtr    = (const int*)d_in[16];

  const int N = in_sizes[0] / HD;
  const int E = in_sizes[13];
  char* ws = (char*)d_ws;

  size_t cur = 0;
  auto alloc = [&](size_t bytes) {
    size_t p = cur;
    cur = (cur + bytes + 255) & ~(size_t)255;
    return p;
  };
  u16* WeT   = (u16*)(ws + alloc((size_t)NT * HD * HD * 2));
  u16* WgT   = (u16*)(ws + alloc((size_t)6 * HD * HD * 2));
  int* deg   = (int*)(ws + alloc((size_t)N * 4));
  int* offA  = (int*)(ws + alloc((size_t)N * 4));
  int* bsum  = (int*)(ws + alloc(1024 * 4));
  u32* elist = (u32*)(ws + alloc((size_t)E * 4));
  size_t base_need = cur;
  u16* P     = (u16*)(ws + alloc((size_t)N * NT * HD * 2));
  const size_t csr_need = cur;
  u16* Hb    = (u16*)(ws + alloc((size_t)N * HD * 2));
  const size_t split_need = cur;

  const int gb = (N + 127) / 128;
  const int NB = (N + 1023) / 1024;

  k_cvt_w<<<(NT * HD * HD + 6 * HD * HD + 255) / 256, 256, 0, stream>>>(
      W_edge, (const float*)d_in[3], (const float*)d_in[5], (const float*)d_in[7],
      (const float*)d_in[9], (const float*)d_in[10], (const float*)d_in[11], WeT, WgT);

  if (ws_size >= csr_need) {
    hipMemsetAsync(deg, 0, (size_t)N * 4, stream);
    k_gemm_edge6<<<gb, 256, 0, stream>>>(X, WeT, b_edge, P, N);
    k_count<<<1024, 256, 0, stream>>>(dst, nePtr, deg);
    k_scan_a<<<NB, 256, 0, stream>>>(deg, offA, bsum, N);
    k_scan_b<<<1, 1024, 0, stream>>>(bsum, NB);
    k_scan_c<<<NB, 256, 0, stream>>>(offA, bsum, N);
    k_fill<<<1024, 256, 0, stream>>>(src, dst, typ, nePtr, offA, elist);
    if (ws_size >= split_need) {
      k_gather<<<(N + 3) / 4, 256, 0, stream>>>(P, deg, offA, elist, Hb, N);
      k_gru19<<<gb, 512, 0, stream>>>(
          X, Hb, WgT, b_ir, b_iz, b_in, b_hn, (float*)d_out, N);
    } else {
      k_gather_gru<<<(N + 63) / 64, 256, 0, stream>>>(
          X, P, deg, offA, elist, WgT, b_ir, b_iz, b_in, b_hn, (float*)d_out, N);
    }
  } else {
    float* agg = (float*)d_out;
    hipMemsetAsync(d_out, 0, (size_t)out_size * sizeof(float), stream);
    size_t pneed = base_need + (size_t)N * NT * HD * 2;
    if (ws_size >= pneed) {
      u16* Pf = (u16*)(ws + base_need);
      k_gemm_edge6<<<gb, 256, 0, stream>>>(X, WeT, b_edge, Pf, N);
      k_scatter<<<2048, 256, 0, stream>>>(Pf, src, dst, typ, nePtr, agg, NT * HD, -1);
      k_gru<<<(N + 63) / 64, 256, 0, stream>>>(X, agg, WgT, b_ir, b_iz, b_in, b_hn, agg, N);
    }
  }
}

// Round 24
// 234.699 us; speedup vs baseline: 1.8061x; 1.8061x over previous
//
#include <hip/hip_runtime.h>
#include <hip/hip_bf16.h>

#define HD 128
#define NT 6

typedef unsigned short u16;
typedef unsigned int u32;
typedef __attribute__((ext_vector_type(8))) short bf16x8;
typedef __attribute__((ext_vector_type(4))) float f32x4;

__device__ __forceinline__ float sigmoidf_(float x) {
  return 1.0f / (1.0f + __expf(-x));
}

// f32 -> bf16 (RNE)
__device__ __forceinline__ u16 f2bf(float x) {
  u32 u = __float_as_uint(x);
  return (u16)((u + 0x7FFFu + ((u >> 16) & 1u)) >> 16);
}
__device__ __forceinline__ float bflo(u32 v) { return __uint_as_float(v << 16); }
__device__ __forceinline__ float bfhi(u32 v) { return __uint_as_float(v & 0xffff0000u); }
__device__ __forceinline__ float bfs(u16 v) { return __uint_as_float((u32)v << 16); }

// XOR swizzle for 256B-row bf16 LDS tiles (involution, both sides).
__device__ __forceinline__ int swz(int p) { return p ^ (((p >> 8) & 7) << 4); }

// ============ weight convert+transpose: W^T bf16 ============
// WeT: [6][128 cols][128 k]; WgT: [6][128][128] (ir,iz,in,hr,hz,hn)
__global__ void k_cvt_w(const float* __restrict__ We,
                        const float* __restrict__ Wir, const float* __restrict__ Wiz,
                        const float* __restrict__ Win, const float* __restrict__ Whr,
                        const float* __restrict__ Whz, const float* __restrict__ Whn,
                        u16* __restrict__ WeT, u16* __restrict__ WgT) {
  int i = blockIdx.x * blockDim.x + threadIdx.x;
  if (i < NT * HD * HD) {
    int c = i >> 7, k = i & 127;                 // WeT[c][k] = We[k][c]
    WeT[i] = f2bf(We[(size_t)k * (NT * HD) + c]);
  } else {
    int j = i - NT * HD * HD;
    if (j < 6 * HD * HD) {
      int m = j >> 14, jj = j & 16383;
      int c = jj >> 7, k = jj & 127;
      const float* W = (m == 0) ? Wir : (m == 1) ? Wiz : (m == 2) ? Win
                     : (m == 3) ? Whr : (m == 4) ? Whz : Whn;
      WgT[j] = f2bf(W[(size_t)k * HD + c]);
    }
  }
}

// ============ Edge projection GEMM, all 6 types per block (proven form) ============
__global__ __launch_bounds__(256) void k_gemm_edge6(
    const float* __restrict__ X, const u16* __restrict__ WeT,
    const float* __restrict__ Be, u16* __restrict__ P, int N)
{
  __shared__ char As[32768];   // 128 rows x 128 k bf16 (swizzled)
  __shared__ char Bs[32768];
  const int tid = threadIdx.x;
  const int row0 = blockIdx.x * 128;

  #pragma unroll
  for (int i = 0; i < 8; ++i) {
    int p = i * 4096 + tid * 16;
    int row = row0 + (p >> 8);
    union { u16 u[8]; bf16x8 v; } ra;
    if (row < N) {
      const float4* s = (const float4*)(X + (size_t)row0 * HD + (p >> 1));
      float4 f0 = s[0], f1 = s[1];
      ra.u[0] = f2bf(f0.x); ra.u[1] = f2bf(f0.y); ra.u[2] = f2bf(f0.z); ra.u[3] = f2bf(f0.w);
      ra.u[4] = f2bf(f1.x); ra.u[5] = f2bf(f1.y); ra.u[6] = f2bf(f1.z); ra.u[7] = f2bf(f1.w);
    } else {
      #pragma unroll
      for (int j = 0; j < 8; ++j) ra.u[j] = 0;
    }
    *(bf16x8*)(As + swz(p)) = ra.v;
  }

  const int l = tid & 63, w = tid >> 6;
  const int m0 = (w >> 1) * 64, n0 = (w & 1) * 64;
  const int lr = l & 15, lg = l >> 4;
  f32x4 zero = {0.f, 0.f, 0.f, 0.f};

  for (int t = 0; t < NT; ++t) {     // compile-time constant -> unrolled
    __syncthreads();
    const char* gB = (const char*)(WeT + (size_t)t * HD * HD);
    #pragma unroll
    for (int i = 0; i < 8; ++i) {
      int p = i * 4096 + tid * 16;
      *(bf16x8*)(Bs + swz(p)) = *(const bf16x8*)(gB + p);
    }
    __syncthreads();

    f32x4 acc[4][4];
    #pragma unroll
    for (int m = 0; m < 4; ++m)
      #pragma unroll
      for (int n = 0; n < 4; ++n) acc[m][n] = zero;

    #pragma unroll
    for (int k = 0; k < 4; ++k) {
      bf16x8 a[4], b[4];
      #pragma unroll
      for (int m = 0; m < 4; ++m)
        a[m] = *(const bf16x8*)(As + swz((m0 + m * 16 + lr) * 256 + k * 64 + lg * 16));
      #pragma unroll
      for (int n = 0; n < 4; ++n)
        b[n] = *(const bf16x8*)(Bs + swz((n0 + n * 16 + lr) * 256 + k * 64 + lg * 16));
      #pragma unroll
      for (int m = 0; m < 4; ++m)
        #pragma unroll
        for (int n = 0; n < 4; ++n)
          acc[m][n] = __builtin_amdgcn_mfma_f32_16x16x32_bf16(a[m], b[n], acc[m][n], 0, 0, 0);
    }

    float bias[4];
    #pragma unroll
    for (int n = 0; n < 4; ++n) bias[n] = Be[t * HD + n0 + n * 16 + lr];
    #pragma unroll
    for (int m = 0; m < 4; ++m) {
      int rbase = row0 + m0 + m * 16 + lg * 4;
      #pragma unroll
      for (int j = 0; j < 4; ++j) {
        int row = rbase + j;
        if (row < N) {
          #pragma unroll
          for (int n = 0; n < 4; ++n)
            P[(size_t)row * (NT * HD) + t * HD + n0 + n * 16 + lr] =
                f2bf(acc[m][n][j] + bias[n]);
        }
      }
    }
  }
}

// ============ CSR build ============
__global__ __launch_bounds__(256) void k_count(const int* __restrict__ dst,
                                               const int* __restrict__ nePtr,
                                               int* __restrict__ deg) {
  const int ne = nePtr[0];
  for (int e = blockIdx.x * blockDim.x + threadIdx.x; e < ne;
       e += gridDim.x * blockDim.x)
    atomicAdd(&deg[dst[e]], 1);
}

__global__ __launch_bounds__(256) void k_scan_a(const int* __restrict__ deg,
                                                int* __restrict__ off,
                                                int* __restrict__ bsum, int N) {
  __shared__ int s[256];
  const int b = blockIdx.x, tid = threadIdx.x;
  const int base = b * 1024 + tid * 4;
  int v0 = 0, v1 = 0, v2 = 0, v3 = 0;
  if (base < N) v0 = deg[base];
  if (base + 1 < N) v1 = deg[base + 1];
  if (base + 2 < N) v2 = deg[base + 2];
  if (base + 3 < N) v3 = deg[base + 3];
  const int sum = v0 + v1 + v2 + v3;
  s[tid] = sum;
  __syncthreads();
  for (int d = 1; d < 256; d <<= 1) {
    int t = (tid >= d) ? s[tid - d] : 0;
    __syncthreads();
    s[tid] += t;
    __syncthreads();
  }
  const int excl = s[tid] - sum;
  if (base < N) off[base] = excl;
  if (base + 1 < N) off[base + 1] = excl + v0;
  if (base + 2 < N) off[base + 2] = excl + v0 + v1;
  if (base + 3 < N) off[base + 3] = excl + v0 + v1 + v2;
  if (tid == 255) bsum[b] = s[255];
}

__global__ void k_scan_b(int* __restrict__ bsum, int nb) {
  __shared__ int s[1024];
  const int tid = threadIdx.x;
  const int v = (tid < nb) ? bsum[tid] : 0;
  s[tid] = v;
  __syncthreads();
  for (int d = 1; d < 1024; d <<= 1) {
    int t = (tid >= d) ? s[tid - d] : 0;
    __syncthreads();
    s[tid] += t;
    __syncthreads();
  }
  if (tid < nb) bsum[tid] = s[tid] - v;   // exclusive
}

__global__ __launch_bounds__(256) void k_scan_c(int* __restrict__ off,
                                                const int* __restrict__ bsum, int N) {
  const int b = blockIdx.x, tid = threadIdx.x;
  const int add = bsum[b];
  const int base = b * 1024 + tid * 4;
  #pragma unroll
  for (int i = 0; i < 4; ++i)
    if (base + i < N) off[base + i] += add;
}

__global__ __launch_bounds__(256) void k_fill(const int* __restrict__ src,
                                              const int* __restrict__ dst,
                                              const int* __restrict__ typ,
                                              const int* __restrict__ nePtr,
                                              int* __restrict__ off,
                                              u32* __restrict__ elist) {
  const int ne = nePtr[0];
  for (int e = blockIdx.x * blockDim.x + threadIdx.x; e < ne;
       e += gridDim.x * blockDim.x) {
    int pos = atomicAdd(&off[dst[e]], 1);
    elist[pos] = (u32)(src[e] * NT + typ[e]);   // P-row index
  }
}

// ============ Standalone gather: one wave per node, masked 4-deep MLP ============
__global__ __launch_bounds__(256) void k_gather(
    const u16* __restrict__ P, const int* __restrict__ deg,
    const int* __restrict__ off, const u32* __restrict__ elist,
    u16* __restrict__ Hb, int N)
{
  const int l = threadIdx.x & 63;
  int wid = (int)((blockIdx.x * blockDim.x + threadIdx.x) >> 6);
  int nw = (int)((gridDim.x * blockDim.x) >> 6);
  for (int n = wid; n < N; n += nw) {
    const int e1 = off[n];
    const int e0 = e1 - deg[n];
    float a0 = 0.f, a1 = 0.f, b0 = 0.f, b1 = 0.f;
    for (int e = e0; e < e1; e += 4) {
      u32 p0 = elist[e];
      u32 p1 = (e + 1 < e1) ? elist[e + 1] : p0;
      u32 p2 = (e + 2 < e1) ? elist[e + 2] : p0;
      u32 p3 = (e + 3 < e1) ? elist[e + 3] : p0;
      u32 v0 = *((const u32*)(P + (size_t)p0 * HD) + l);
      u32 v1 = *((const u32*)(P + (size_t)p1 * HD) + l);
      u32 v2 = *((const u32*)(P + (size_t)p2 * HD) + l);
      u32 v3 = *((const u32*)(P + (size_t)p3 * HD) + l);
      if (e + 1 >= e1) v1 = 0;
      if (e + 2 >= e1) v2 = 0;
      if (e + 3 >= e1) v3 = 0;
      a0 += bflo(v0); a1 += bfhi(v0);
      b0 += bflo(v1); b1 += bfhi(v1);
      a0 += bflo(v2); a1 += bfhi(v2);
      b0 += bflo(v3); b1 += bfhi(v3);
    }
    a0 += b0; a1 += b1;
    u32 hp = ((u32)f2bf(a1) << 16) | (u32)f2bf(a0);
    *((u32*)(Hb + (size_t)n * HD) + l) = hp;
  }
}

// ============ GRU v15b: champion. dbuf W + reg prefetch + setprio ============
// 512 thr / 8 waves; wave = 32 rows x 64 cols. Per phase:
//   loadW(next) ; setprio(1) sweep(curBuf) setprio(0) ; writeW(otherBuf) ; barrier.
__global__ __launch_bounds__(512) void k_gru15(
    const float* __restrict__ X, const u16* __restrict__ Hb,
    const u16* __restrict__ WgT,   // [6][128 cols][128 k]: ir,iz,in,hr,hz,hn
    const float* __restrict__ bir, const float* __restrict__ biz,
    const float* __restrict__ bin_, const float* __restrict__ bhn,
    float* __restrict__ out, int N)
{
  __shared__ char Xs[32768];     // 128 rows x 128 k bf16 (swizzled)
  __shared__ char Hs[32768];
  __shared__ char Bs[2][32768];  // double-buffered gate W^T tile
  const int tid = threadIdx.x;
  const int row0 = blockIdx.x * 128;

  // ---- stage X (f32->bf16) and H (bf16 copy) tiles, once ----
  #pragma unroll
  for (int i = 0; i < 4; ++i) {
    int p = i * 8192 + tid * 16;
    int row = row0 + (p >> 8);
    union { u16 u[8]; bf16x8 v; } rx, rh;
    if (row < N) {
      const float4* sx = (const float4*)(X + (size_t)row0 * HD + (p >> 1));
      float4 x0 = sx[0], x1 = sx[1];
      rx.u[0] = f2bf(x0.x); rx.u[1] = f2bf(x0.y); rx.u[2] = f2bf(x0.z); rx.u[3] = f2bf(x0.w);
      rx.u[4] = f2bf(x1.x); rx.u[5] = f2bf(x1.y); rx.u[6] = f2bf(x1.z); rx.u[7] = f2bf(x1.w);
      rh.v = *(const bf16x8*)((const char*)Hb + (size_t)row0 * 256 + p);
    } else {
      #pragma unroll
      for (int j = 0; j < 8; ++j) { rx.u[j] = 0; rh.u[j] = 0; }
    }
    *(bf16x8*)(Xs + swz(p)) = rx.v;
    *(bf16x8*)(Hs + swz(p)) = rh.v;
  }

  const int l = tid & 63, w = tid >> 6;
  const int m0 = (w >> 1) * 32;          // 4 row-slabs of 32
  const int n0 = (w & 1) * 64;           // 2 col-halves of 64
  const int lr = l & 15, lg = l >> 4;
  f32x4 zero = {0.f, 0.f, 0.f, 0.f};

  // ---- register prefetch buffer (64B/thread per gate tile) ----
  bf16x8 wreg[4];
  auto loadW = [&](int g) {
    const char* gp = (const char*)(WgT + (size_t)g * HD * HD);
    #pragma unroll
    for (int i = 0; i < 4; ++i)
      wreg[i] = *(const bf16x8*)(gp + i * 8192 + tid * 16);
  };
  auto writeW = [&](int buf) {
    #pragma unroll
    for (int i = 0; i < 4; ++i) {
      int p = i * 8192 + tid * 16;
      *(bf16x8*)(Bs[buf] + swz(p)) = wreg[i];
    }
  };

  auto sweep = [&](const char* Ab, int buf, f32x4 (&acc)[2][4]) {
    #pragma unroll
    for (int m = 0; m < 2; ++m)
      #pragma unroll
      for (int n = 0; n < 4; ++n) acc[m][n] = zero;
    __builtin_amdgcn_s_setprio(1);
    #pragma unroll
    for (int k = 0; k < 4; ++k) {
      bf16x8 a[2], b[4];
      #pragma unroll
      for (int m = 0; m < 2; ++m)
        a[m] = *(const bf16x8*)(Ab + swz((m0 + m * 16 + lr) * 256 + k * 64 + lg * 16));
      #pragma unroll
      for (int n = 0; n < 4; ++n)
        b[n] = *(const bf16x8*)(Bs[buf] + swz((n0 + n * 16 + lr) * 256 + k * 64 + lg * 16));
      #pragma unroll
      for (int m = 0; m < 2; ++m)
        #pragma unroll
        for (int n = 0; n < 4; ++n)
          acc[m][n] = __builtin_amdgcn_mfma_f32_16x16x32_bf16(a[m], b[n], acc[m][n], 0, 0, 0);
    }
    __builtin_amdgcn_s_setprio(0);
  };

  f32x4 t1[2][4], t2[2][4], rg[2][4], nn[2][4];
  float bv[4];
  auto ldBias = [&](const float* bp) {
    #pragma unroll
    for (int n = 0; n < 4; ++n) bv[n] = bp[n0 + n * 16 + lr];
  };

  // prologue: Wir -> buf0
  loadW(0); writeW(0);
  __syncthreads();

  // gate order: ir(0)b0, hr(3)b1, hn(5)b0, in(2)b1, iz(1)b0, hz(4)b1
  // phase: loadW(next); sweep(cur buf); writeW(other buf); barrier.
  loadW(3);
  sweep(Xs, 0, t1);                 // X@Wir
  writeW(1);
  __syncthreads();

  loadW(5);
  sweep(Hs, 1, t2);                 // H@Whr
  writeW(0);
  ldBias(bir);
  #pragma unroll
  for (int m = 0; m < 2; ++m)
    #pragma unroll
    for (int n = 0; n < 4; ++n)
      #pragma unroll
      for (int j = 0; j < 4; ++j)
        rg[m][n][j] = sigmoidf_(t1[m][n][j] + bv[n] + t2[m][n][j]);
  __syncthreads();

  loadW(2);
  sweep(Hs, 0, t2);                 // H@Whn
  writeW(1);
  ldBias(bhn);
  #pragma unroll
  for (int m = 0; m < 2; ++m)
    #pragma unroll
    for (int n = 0; n < 4; ++n)
      #pragma unroll
      for (int j = 0; j < 4; ++j)
        rg[m][n][j] *= (t2[m][n][j] + bv[n]);
  __syncthreads();

  loadW(1);
  sweep(Xs, 1, t1);                 // X@Win
  writeW(0);
  ldBias(bin_);
  #pragma unroll
  for (int m = 0; m < 2; ++m)
    #pragma unroll
    for (int n = 0; n < 4; ++n)
      #pragma unroll
      for (int j = 0; j < 4; ++j)
        nn[m][n][j] = tanhf(t1[m][n][j] + bv[n] + rg[m][n][j]);
  __syncthreads();

  loadW(4);
  sweep(Xs, 0, t1);                 // X@Wiz
  writeW(1);
  __syncthreads();

  sweep(Hs, 1, t2);                 // H@Whz
  ldBias(biz);
  #pragma unroll
  for (int m = 0; m < 2; ++m) {
    #pragma unroll
    for (int j = 0; j < 4; ++j) {
      int row = row0 + m0 + m * 16 + lg * 4 + j;
      if (row < N) {
        #pragma unroll
        for (int n = 0; n < 4; ++n) {
          int col = n0 + n * 16 + lr;
          float z = sigmoidf_(t1[m][n][j] + bv[n] + t2[m][n][j]);
          float h = bfs(Hb[(size_t)row * HD + col]);    // L3-hot, coalesced
          out[(size_t)row * HD + col] = (1.0f - z) * nn[m][n][j] + z * h;
        }
      }
    }
  }
}

// ============ Fused gather+GRU (mid-tier fallback) ============
__global__ __launch_bounds__(256) void k_gather_gru(
    const float* __restrict__ X, const u16* __restrict__ P,
    const int* __restrict__ deg, const int* __restrict__ off,
    const u32* __restrict__ elist, const u16* __restrict__ WgT,
    const float* __restrict__ bir, const float* __restrict__ biz,
    const float* __restrict__ bin_, const float* __restrict__ bhn,
    float* __restrict__ out, int N)
{
  __shared__ char Xs[16384];
  __shared__ char Hs[16384];
  const int tid = threadIdx.x;
  const int l = tid & 63, w = tid >> 6;
  const int row0 = blockIdx.x * 64;
  const int wr0 = w * 16;

  #pragma unroll
  for (int it = 0; it < 4; ++it) {
    int chunk = it * 64 + l;
    int r = chunk >> 4, seg = chunk & 15;
    int grow = row0 + wr0 + r;
    union { u16 u[8]; bf16x8 v; } rx;
    if (grow < N) {
      const float4* sx = (const float4*)(X + (size_t)grow * HD + seg * 8);
      float4 x0 = sx[0], x1 = sx[1];
      rx.u[0] = f2bf(x0.x); rx.u[1] = f2bf(x0.y); rx.u[2] = f2bf(x0.z); rx.u[3] = f2bf(x0.w);
      rx.u[4] = f2bf(x1.x); rx.u[5] = f2bf(x1.y); rx.u[6] = f2bf(x1.z); rx.u[7] = f2bf(x1.w);
    } else {
      #pragma unroll
      for (int j = 0; j < 8; ++j) rx.u[j] = 0;
    }
    *(bf16x8*)(Xs + swz((wr0 + r) * 256 + seg * 16)) = rx.v;
  }

  for (int i = 0; i < 16; ++i) {
    int n = row0 + wr0 + i;
    float a0 = 0.f, a1 = 0.f;
    if (n < N) {
      int e1 = off[n];
      for (int e = e1 - deg[n]; e < e1; e += 4) {
        u32 p0 = elist[e];
        u32 p1 = (e + 1 < e1) ? elist[e + 1] : p0;
        u32 p2 = (e + 2 < e1) ? elist[e + 2] : p0;
        u32 p3 = (e + 3 < e1) ? elist[e + 3] : p0;
        u32 v0 = *((const u32*)(P + (size_t)p0 * HD) + l);
        u32 v1 = *((const u32*)(P + (size_t)p1 * HD) + l);
        u32 v2 = *((const u32*)(P + (size_t)p2 * HD) + l);
        u32 v3 = *((const u32*)(P + (size_t)p3 * HD) + l);
        if (e + 1 >= e1) v1 = 0;
        if (e + 2 >= e1) v2 = 0;
        if (e + 3 >= e1) v3 = 0;
        a0 += bflo(v0) + bflo(v1) + bflo(v2) + bflo(v3);
        a1 += bfhi(v0) + bfhi(v1) + bfhi(v2) + bfhi(v3);
      }
    }
    u32 hp = ((u32)f2bf(a1) << 16) | (u32)f2bf(a0);
    *(u32*)(Hs + swz((wr0 + i) * 256 + l * 4)) = hp;
  }

  const int lr = l & 15, lg = l >> 4;
  const int rloc = wr0;

  f32x4 zero = {0.f, 0.f, 0.f, 0.f};
  auto sweep = [&](const char* Ab, const u16* WT, f32x4* acc) {
    #pragma unroll
    for (int n = 0; n < 8; ++n) acc[n] = zero;
    #pragma unroll
    for (int k = 0; k < 4; ++k) {
      bf16x8 a = *(const bf16x8*)(Ab + swz((rloc + lr) * 256 + k * 64 + lg * 16));
      #pragma unroll
      for (int n = 0; n < 8; ++n) {
        bf16x8 b = *(const bf16x8*)(WT + (size_t)(n * 16 + lr) * HD + k * 32 + lg * 8);
        acc[n] = __builtin_amdgcn_mfma_f32_16x16x32_bf16(a, b, acc[n], 0, 0, 0);
      }
    }
  };

  f32x4 t1[8], t2[8], rg[8], nn[8];
  float bv[8];

  sweep(Xs, WgT + 0 * HD * HD, t1);
  sweep(Hs, WgT + 3 * HD * HD, t2);
  #pragma unroll
  for (int n = 0; n < 8; ++n) bv[n] = bir[n * 16 + lr];
  #pragma unroll
  for (int n = 0; n < 8; ++n)
    #pragma unroll
    for (int j = 0; j < 4; ++j) rg[n][j] = sigmoidf_(t1[n][j] + bv[n] + t2[n][j]);

  sweep(Hs, WgT + 5 * HD * HD, t2);
  #pragma unroll
  for (int n = 0; n < 8; ++n) bv[n] = bhn[n * 16 + lr];
  #pragma unroll
  for (int n = 0; n < 8; ++n)
    #pragma unroll
    for (int j = 0; j < 4; ++j) rg[n][j] *= (t2[n][j] + bv[n]);

  sweep(Xs, WgT + 2 * HD * HD, t1);
  #pragma unroll
  for (int n = 0; n < 8; ++n) bv[n] = bin_[n * 16 + lr];
  #pragma unroll
  for (int n = 0; n < 8; ++n)
    #pragma unroll
    for (int j = 0; j < 4; ++j) nn[n][j] = tanhf(t1[n][j] + bv[n] + rg[n][j]);

  sweep(Xs, WgT + 1 * HD * HD, t1);
  sweep(Hs, WgT + 4 * HD * HD, t2);
  #pragma unroll
  for (int n = 0; n < 8; ++n) bv[n] = biz[n * 16 + lr];
  #pragma unroll
  for (int n = 0; n < 8; ++n) {
    #pragma unroll
    for (int j = 0; j < 4; ++j) {
      int row = row0 + rloc + lg * 4 + j;
      if (row < N) {
        float z = sigmoidf_(t1[n][j] + bv[n] + t2[n][j]);
        u16 hu = *(const u16*)(Hs + swz((rloc + lg * 4 + j) * 256 + (n * 16 + lr) * 2));
        out[(size_t)row * HD + n * 16 + lr] = (1.0f - z) * nn[n][j] + z * bfs(hu);
      }
    }
  }
}

// ============ Lowest-tier fallback: atomic scatter + f32-agg GRU ============
__global__ __launch_bounds__(256) void k_scatter(
    const u16* __restrict__ P, const int* __restrict__ src,
    const int* __restrict__ dst, const int* __restrict__ typ,
    const int* __restrict__ nePtr, float* __restrict__ agg,
    int ldP, int fixedType)
{
  const int ne = nePtr[0];
  const int lane = threadIdx.x & 63;
  const int wid = (int)((blockIdx.x * blockDim.x + threadIdx.x) >> 6);
  const int nw = (int)((gridDim.x * blockDim.x) >> 6);
  for (int e = wid; e < ne; e += nw) {
    const int t = typ[e];
    if (fixedType >= 0 && t != fixedType) continue;
    const size_t po = (ldP == HD) ? (size_t)src[e] * HD
                                  : (size_t)src[e] * (NT * HD) + (size_t)t * HD;
    u32 v = *(const u32*)(P + po + lane * 2);
    float* o = agg + (size_t)dst[e] * HD + lane * 2;
    unsafeAtomicAdd(o, bflo(v));
    unsafeAtomicAdd(o + 1, bfhi(v));
  }
}

__global__ __launch_bounds__(256) void k_gru(
    const float* __restrict__ X, const float* __restrict__ agg,
    const u16* __restrict__ WgT,
    const float* __restrict__ bir, const float* __restrict__ biz,
    const float* __restrict__ bin_, const float* __restrict__ bhn,
    float* __restrict__ out, int N)
{
  __shared__ char Xs[16384];
  __shared__ char Hs[16384];
  const int tid = threadIdx.x;
  const int row0 = blockIdx.x * 64;

  #pragma unroll
  for (int i = 0; i < 4; ++i) {
    int p = i * 4096 + tid * 16;
    int row = row0 + (p >> 8);
    union { u16 u[8]; bf16x8 v; } rx, rh;
    if (row < N) {
      const float4* sx = (const float4*)(X + (size_t)row0 * HD + (p >> 1));
      const float4* sh = (const float4*)(agg + (size_t)row0 * HD + (p >> 1));
      float4 x0 = sx[0], x1 = sx[1], h0 = sh[0], h1 = sh[1];
      rx.u[0] = f2bf(x0.x); rx.u[1] = f2bf(x0.y); rx.u[2] = f2bf(x0.z); rx.u[3] = f2bf(x0.w);
      rx.u[4] = f2bf(x1.x); rx.u[5] = f2bf(x1.y); rx.u[6] = f2bf(x1.z); rx.u[7] = f2bf(x1.w);
      rh.u[0] = f2bf(h0.x); rh.u[1] = f2bf(h0.y); rh.u[2] = f2bf(h0.z); rh.u[3] = f2bf(h0.w);
      rh.u[4] = f2bf(h1.x); rh.u[5] = f2bf(h1.y); rh.u[6] = f2bf(h1.z); rh.u[7] = f2bf(h1.w);
    } else {
      #pragma unroll
      for (int j = 0; j < 8; ++j) { rx.u[j] = 0; rh.u[j] = 0; }
    }
    *(bf16x8*)(Xs + swz(p)) = rx.v;
    *(bf16x8*)(Hs + swz(p)) = rh.v;
  }
  __syncthreads();

  const int l = tid & 63, w = tid >> 6;
  const int lr = l & 15, lg = l >> 4;
  const int rloc = w * 16;

  f32x4 zero = {0.f, 0.f, 0.f, 0.f};
  auto sweep = [&](const char* Ab, const u16* WT, f32x4* acc) {
    #pragma unroll
    for (int n = 0; n < 8; ++n) acc[n] = zero;
    #pragma unroll
    for (int k = 0; k < 4; ++k) {
      bf16x8 a = *(const bf16x8*)(Ab + swz((rloc + lr) * 256 + k * 64 + lg * 16));
      #pragma unroll
      for (int n = 0; n < 8; ++n) {
        bf16x8 b = *(const bf16x8*)(WT + (size_t)(n * 16 + lr) * HD + k * 32 + lg * 8);
        acc[n] = __builtin_amdgcn_mfma_f32_16x16x32_bf16(a, b, acc[n], 0, 0, 0);
      }
    }
  };

  f32x4 t1[8], t2[8], rg[8], nn[8];
  float bv[8];

  sweep(Xs, WgT + 0 * HD * HD, t1);
  sweep(Hs, WgT + 3 * HD * HD, t2);
  #pragma unroll
  for (int n = 0; n < 8; ++n) bv[n] = bir[n * 16 + lr];
  #pragma unroll
  for (int n = 0; n < 8; ++n)
    #pragma unroll
    for (int j = 0; j < 4; ++j) rg[n][j] = sigmoidf_(t1[n][j] + bv[n] + t2[n][j]);

  sweep(Hs, WgT + 5 * HD * HD, t2);
  #pragma unroll
  for (int n = 0; n < 8; ++n) bv[n] = bhn[n * 16 + lr];
  #pragma unroll
  for (int n = 0; n < 8; ++n)
    #pragma unroll
    for (int j = 0; j < 4; ++j) rg[n][j] *= (t2[n][j] + bv[n]);

  sweep(Xs, WgT + 2 * HD * HD, t1);
  #pragma unroll
  for (int n = 0; n < 8; ++n) bv[n] = bin_[n * 16 + lr];
  #pragma unroll
  for (int n = 0; n < 8; ++n)
    #pragma unroll
    for (int j = 0; j < 4; ++j) nn[n][j] = tanhf(t1[n][j] + bv[n] + rg[n][j]);

  sweep(Xs, WgT + 1 * HD * HD, t1);
  sweep(Hs, WgT + 4 * HD * HD, t2);
  #pragma unroll
  for (int n = 0; n < 8; ++n) bv[n] = biz[n * 16 + lr];
  #pragma unroll
  for (int n = 0; n < 8; ++n) {
    #pragma unroll
    for (int j = 0; j < 4; ++j) {
      int row = row0 + rloc + lg * 4 + j;
      if (row < N) {
        float z = sigmoidf_(t1[n][j] + bv[n] + t2[n][j]);
        float h = agg[(size_t)row * HD + n * 16 + lr];
        out[(size_t)row * HD + n * 16 + lr] = (1.0f - z) * nn[n][j] + z * h;
      }
    }
  }
}

extern "C" void kernel_launch(void* const* d_in, const int* in_sizes, int n_in,
                              void* d_out, int out_size, void* d_ws, size_t ws_size,
                              hipStream_t stream) {
  const float* X      = (const float*)d_in[0];
  const float* W_edge = (const float*)d_in[1];
  const float* b_edge = (const float*)d_in[2];
  const float* b_ir   = (const float*)d_in[4];
  const float* b_iz   = (const float*)d_in[6];
  const float* b_in   = (const float*)d_in[8];
  const float* b_hn   = (const float*)d_in[12];
  const int* src      = (const int*)d_in[13];
  const int* dst      = (const int*)d_in[14];
  const int* typ      = (const int*)d_in[15];
  const int* nePtr    = (const int*)d_in[16];

  const int N = in_sizes[0] / HD;
  const int E = in_sizes[13];
  char* ws = (char*)d_ws;

  size_t cur = 0;
  auto alloc = [&](size_t bytes) {
    size_t p = cur;
    cur = (cur + bytes + 255) & ~(size_t)255;
    return p;
  };
  u16* WeT   = (u16*)(ws + alloc((size_t)NT * HD * HD * 2));
  u16* WgT   = (u16*)(ws + alloc((size_t)6 * HD * HD * 2));
  int* deg   = (int*)(ws + alloc((size_t)N * 4));
  int* offA  = (int*)(ws + alloc((size_t)N * 4));
  int* bsum  = (int*)(ws + alloc(1024 * 4));
  u32* elist = (u32*)(ws + alloc((size_t)E * 4));
  size_t base_need = cur;
  u16* P     = (u16*)(ws + alloc((size_t)N * NT * HD * 2));
  const size_t csr_need = cur;
  u16* Hb    = (u16*)(ws + alloc((size_t)N * HD * 2));
  const size_t split_need = cur;

  const int gb = (N + 127) / 128;
  const int NB = (N + 1023) / 1024;

  k_cvt_w<<<(NT * HD * HD + 6 * HD * HD + 255) / 256, 256, 0, stream>>>(
      W_edge, (const float*)d_in[3], (const float*)d_in[5], (const float*)d_in[7],
      (const float*)d_in[9], (const float*)d_in[10], (const float*)d_in[11], WeT, WgT);

  if (ws_size >= csr_need) {
    hipMemsetAsync(deg, 0, (size_t)N * 4, stream);
    k_gemm_edge6<<<gb, 256, 0, stream>>>(X, WeT, b_edge, P, N);
    k_count<<<1024, 256, 0, stream>>>(dst, nePtr, deg);
    k_scan_a<<<NB, 256, 0, stream>>>(deg, offA, bsum, N);
    k_scan_b<<<1, 1024, 0, stream>>>(bsum, NB);
    k_scan_c<<<NB, 256, 0, stream>>>(offA, bsum, N);
    k_fill<<<1024, 256, 0, stream>>>(src, dst, typ, nePtr, offA, elist);
    if (ws_size >= split_need) {
      k_gather<<<(N + 3) / 4, 256, 0, stream>>>(P, deg, offA, elist, Hb, N);
      k_gru15<<<gb, 512, 0, stream>>>(
          X, Hb, WgT, b_ir, b_iz, b_in, b_hn, (float*)d_out, N);
    } else {
      k_gather_gru<<<(N + 63) / 64, 256, 0, stream>>>(
          X, P, deg, offA, elist, WgT, b_ir, b_iz, b_in, b_hn, (float*)d_out, N);
    }
  } else {
    float* agg = (float*)d_out;
    hipMemsetAsync(d_out, 0, (size_t)out_size * sizeof(float), stream);
    size_t pneed = base_need + (size_t)N * NT * HD * 2;
    if (ws_size >= pneed) {
      u16* Pf = (u16*)(ws + base_need);
      k_gemm_edge6<<<gb, 256, 0, stream>>>(X, WeT, b_edge, Pf, N);
      k_scatter<<<2048, 256, 0, stream>>>(Pf, src, dst, typ, nePtr, agg, NT * HD, -1);
      k_gru<<<(N + 63) / 64, 256, 0, stream>>>(X, agg, WgT, b_ir, b_iz, b_in, b_hn, agg, N);
    }
  }
}